// Round 1
// baseline (2083.633 us; speedup 1.0000x reference)
//
#include <hip/hip_runtime.h>
#include <hip/hip_bf16.h>

namespace {
constexpr int kN = 50000;   // nodes
constexpr int kE = 250000;  // edges
constexpr int kG = 2500;    // graphs

__device__ __forceinline__ float sigmoidf_(float x) { return 1.0f / (1.0f + expf(-x)); }

// starts[g] = first node index with batch[n] >= g (batch is sorted). g in [0, kG].
__global__ void k_starts(const int* __restrict__ batch, int* __restrict__ starts) {
  int g = blockIdx.x * blockDim.x + threadIdx.x;
  if (g > kG) return;
  int lo = 0, hi = kN;
  while (lo < hi) {
    int mid = (lo + hi) >> 1;
    if (batch[mid] < g) lo = mid + 1; else hi = mid;
  }
  starts[g] = lo;
}

// h[n,:] = relu(x[n,:] @ lin_w + lin_b)   [N,32] = [N,32]@[32,32]
__global__ __launch_bounds__(256) void k_node_init(const float* __restrict__ x,
                                                   const float* __restrict__ lin_w,
                                                   const float* __restrict__ lin_b,
                                                   float* __restrict__ h) {
  __shared__ float ws[32 * 32];
  __shared__ float bs[32];
  for (int i = threadIdx.x; i < 1024; i += 256) ws[i] = lin_w[i];
  if (threadIdx.x < 32) bs[threadIdx.x] = lin_b[threadIdx.x];
  __syncthreads();
  int n = blockIdx.x * 256 + threadIdx.x;
  if (n >= kN) return;
  float xv[32];
  const float4* xp = (const float4*)(x + (size_t)n * 32);
#pragma unroll
  for (int i = 0; i < 8; ++i) {
    float4 v = xp[i];
    xv[4 * i + 0] = v.x; xv[4 * i + 1] = v.y; xv[4 * i + 2] = v.z; xv[4 * i + 3] = v.w;
  }
  float acc[32];
#pragma unroll
  for (int o = 0; o < 32; ++o) acc[o] = bs[o];
  for (int i = 0; i < 32; ++i) {
    float a = xv[i];
    const float4* wr = (const float4*)&ws[i * 32];
#pragma unroll
    for (int o4 = 0; o4 < 8; ++o4) {
      float4 w = wr[o4];
      acc[4 * o4 + 0] = fmaf(a, w.x, acc[4 * o4 + 0]);
      acc[4 * o4 + 1] = fmaf(a, w.y, acc[4 * o4 + 1]);
      acc[4 * o4 + 2] = fmaf(a, w.z, acc[4 * o4 + 2]);
      acc[4 * o4 + 3] = fmaf(a, w.w, acc[4 * o4 + 3]);
    }
  }
  float4* hp = (float4*)(h + (size_t)n * 32);
#pragma unroll
  for (int i = 0; i < 8; ++i) {
    float4 v;
    v.x = fmaxf(acc[4 * i + 0], 0.f);
    v.y = fmaxf(acc[4 * i + 1], 0.f);
    v.z = fmaxf(acc[4 * i + 2], 0.f);
    v.w = fmaxf(acc[4 * i + 3], 0.f);
    hp[i] = v;
  }
}

// eh[e,:] = relu(edge_attr[e,:] @ e_w1 + e_b1)   [E,64] = [E,16]@[16,64]
__global__ __launch_bounds__(256) void k_edge_h(const float* __restrict__ ea,
                                                const float* __restrict__ w1,
                                                const float* __restrict__ b1,
                                                float* __restrict__ eh) {
  __shared__ float ws[16 * 64];
  __shared__ float bs[64];
  for (int i = threadIdx.x; i < 1024; i += 256) ws[i] = w1[i];
  if (threadIdx.x < 64) bs[threadIdx.x] = b1[threadIdx.x];
  __syncthreads();
  int e = blockIdx.x * 256 + threadIdx.x;
  if (e >= kE) return;
  float av[16];
  const float4* ap = (const float4*)(ea + (size_t)e * 16);
#pragma unroll
  for (int i = 0; i < 4; ++i) {
    float4 v = ap[i];
    av[4 * i + 0] = v.x; av[4 * i + 1] = v.y; av[4 * i + 2] = v.z; av[4 * i + 3] = v.w;
  }
  float acc[64];
#pragma unroll
  for (int o = 0; o < 64; ++o) acc[o] = bs[o];
  for (int i = 0; i < 16; ++i) {
    float a = av[i];
    const float4* wr = (const float4*)&ws[i * 64];
#pragma unroll
    for (int o4 = 0; o4 < 16; ++o4) {
      float4 w = wr[o4];
      acc[4 * o4 + 0] = fmaf(a, w.x, acc[4 * o4 + 0]);
      acc[4 * o4 + 1] = fmaf(a, w.y, acc[4 * o4 + 1]);
      acc[4 * o4 + 2] = fmaf(a, w.z, acc[4 * o4 + 2]);
      acc[4 * o4 + 3] = fmaf(a, w.w, acc[4 * o4 + 3]);
    }
  }
  float4* op = (float4*)(eh + (size_t)e * 64);
#pragma unroll
  for (int i = 0; i < 16; ++i) {
    float4 v;
    v.x = fmaxf(acc[4 * i + 0], 0.f);
    v.y = fmaxf(acc[4 * i + 1], 0.f);
    v.z = fmaxf(acc[4 * i + 2], 0.f);
    v.w = fmaxf(acc[4 * i + 3], 0.f);
    op[i] = v;
  }
}

__global__ void k_deg(const int* __restrict__ dst, float* __restrict__ denom) {
  int e = blockIdx.x * blockDim.x + threadIdx.x;
  if (e < kE) atomicAdd(&denom[dst[e]], 1.0f);
}

// W[eL, f] = b2[f] + sum_k eh[e0+eL, k] * w2[k, f], f-tile of 128 per blockIdx.y
// tile: 64 edges x 128 f, block 256 threads, each thread 8 edges x 4 f.
__global__ __launch_bounds__(256) void k_we_gemm(const float* __restrict__ eh,
                                                 const float* __restrict__ w2,
                                                 const float* __restrict__ b2,
                                                 float* __restrict__ W, int e0, int ne) {
  __shared__ float ehs[64][64];
  __shared__ float w2s[64][128];
  const int f0 = blockIdx.y * 128;
  const int ebase = blockIdx.x * 64;
  const int t = threadIdx.x;
#pragma unroll
  for (int i = 0; i < 4; ++i) {  // 1024 float4 of ehs
    int idx = t + i * 256;
    int r = idx >> 4, c4 = idx & 15;
    int eL = ebase + r;
    float4 v = make_float4(0.f, 0.f, 0.f, 0.f);
    if (eL < ne) v = *(const float4*)(eh + (size_t)(e0 + eL) * 64 + c4 * 4);
    *(float4*)&ehs[r][c4 * 4] = v;
  }
#pragma unroll
  for (int i = 0; i < 8; ++i) {  // 2048 float4 of w2s
    int idx = t + i * 256;
    int k = idx >> 5, c4 = idx & 31;
    *(float4*)&w2s[k][c4 * 4] = *(const float4*)(w2 + (size_t)k * 1024 + f0 + c4 * 4);
  }
  __syncthreads();
  const int oq = t & 31;   // f-quad 0..31
  const int eg = t >> 5;   // edge group 0..7 (8 edges each)
  float acc[8][4];
  {
    float4 bv = *(const float4*)(b2 + f0 + oq * 4);
#pragma unroll
    for (int m = 0; m < 8; ++m) {
      acc[m][0] = bv.x; acc[m][1] = bv.y; acc[m][2] = bv.z; acc[m][3] = bv.w;
    }
  }
#pragma unroll 8
  for (int k = 0; k < 64; ++k) {
    float4 wv = *(const float4*)&w2s[k][oq * 4];
#pragma unroll
    for (int m = 0; m < 8; ++m) {
      float a = ehs[eg * 8 + m][k];
      acc[m][0] = fmaf(a, wv.x, acc[m][0]);
      acc[m][1] = fmaf(a, wv.y, acc[m][1]);
      acc[m][2] = fmaf(a, wv.z, acc[m][2]);
      acc[m][3] = fmaf(a, wv.w, acc[m][3]);
    }
  }
#pragma unroll
  for (int m = 0; m < 8; ++m) {
    int eL = ebase + eg * 8 + m;
    if (eL < ne)
      *(float4*)(W + (size_t)eL * 1024 + f0 + oq * 4) =
          make_float4(acc[m][0], acc[m][1], acc[m][2], acc[m][3]);
  }
}

// msg[e,o] = sum_a h[src[e],a] * W[eL, a*32+o]; atomically accumulate into agg[dst]
// one half-wave (32 lanes) per edge
__global__ void k_msg(const float* __restrict__ W, const float* __restrict__ h,
                      const int* __restrict__ src, const int* __restrict__ dst,
                      float* __restrict__ agg, int e0, int ne) {
  int tid = blockIdx.x * blockDim.x + threadIdx.x;
  int eL = tid >> 5;
  if (eL >= ne) return;
  int o = threadIdx.x & 31;
  int ge = e0 + eL;
  int s = src[ge], d = dst[ge];
  float hv = h[(size_t)s * 32 + o];
  const float* Wp = W + (size_t)eL * 1024 + o;
  float acc = 0.f;
#pragma unroll
  for (int a = 0; a < 32; ++a) {
    float xa = __shfl(hv, a, 32);
    acc = fmaf(xa, Wp[a * 32], acc);
  }
  atomicAdd(&agg[(size_t)d * 32 + o], acc);
}

// Insurance fallback: compute msg directly from eh & w2 (no W storage).
__global__ void k_msg_direct(const float* __restrict__ eh, const float* __restrict__ w2,
                             const float* __restrict__ b2, const float* __restrict__ h,
                             const int* __restrict__ src, const int* __restrict__ dst,
                             float* __restrict__ agg) {
  int tid = blockIdx.x * blockDim.x + threadIdx.x;
  int e = tid >> 5;
  if (e >= kE) return;
  int o = threadIdx.x & 31;
  int s = src[e], d = dst[e];
  float hv = h[(size_t)s * 32 + o];
  float acc = 0.f;
  for (int a = 0; a < 32; ++a) {
    float xa = __shfl(hv, a, 32);
    float wsum = b2[a * 32 + o];
    for (int k = 0; k < 64; ++k)
      wsum = fmaf(eh[(size_t)e * 64 + k], w2[(size_t)k * 1024 + a * 32 + o], wsum);
    acc = fmaf(xa, wsum, acc);
  }
  atomicAdd(&agg[(size_t)d * 32 + o], acc);
}

// GRU cell, in-place h update. m = relu(agg/denom)
__global__ __launch_bounds__(256) void k_gru(float* __restrict__ h, const float* __restrict__ agg,
                                             const float* __restrict__ denom,
                                             const float* __restrict__ Wih, const float* __restrict__ Whh,
                                             const float* __restrict__ bih, const float* __restrict__ bhh) {
  __shared__ float wih_s[96 * 32];
  __shared__ float whh_s[96 * 32];
  __shared__ float bih_s[96], bhh_s[96];
  for (int i = threadIdx.x; i < 96 * 32; i += 256) { wih_s[i] = Wih[i]; whh_s[i] = Whh[i]; }
  for (int i = threadIdx.x; i < 96; i += 256) { bih_s[i] = bih[i]; bhh_s[i] = bhh[i]; }
  __syncthreads();
  int n = blockIdx.x * 256 + threadIdx.x;
  if (n >= kN) return;
  float dn = fmaxf(denom[n], 1.0f);
  float m[32], hv[32];
  const float4* ap = (const float4*)(agg + (size_t)n * 32);
  const float4* hp = (const float4*)(h + (size_t)n * 32);
#pragma unroll
  for (int i = 0; i < 8; ++i) {
    float4 a = ap[i];
    m[4 * i + 0] = fmaxf(a.x / dn, 0.f);
    m[4 * i + 1] = fmaxf(a.y / dn, 0.f);
    m[4 * i + 2] = fmaxf(a.z / dn, 0.f);
    m[4 * i + 3] = fmaxf(a.w / dn, 0.f);
    float4 b = hp[i];
    hv[4 * i + 0] = b.x; hv[4 * i + 1] = b.y; hv[4 * i + 2] = b.z; hv[4 * i + 3] = b.w;
  }
  float rr[32], zz[32];
#pragma unroll 4
  for (int j = 0; j < 32; ++j) {  // r gate: rows j
    float accA = bih_s[j], accB = bhh_s[j];
    const float4* wi = (const float4*)&wih_s[j * 32];
    const float4* wh = (const float4*)&whh_s[j * 32];
#pragma unroll
    for (int i = 0; i < 8; ++i) {
      float4 a = wi[i], b = wh[i];
      accA = fmaf(m[4 * i + 0], a.x, accA); accA = fmaf(m[4 * i + 1], a.y, accA);
      accA = fmaf(m[4 * i + 2], a.z, accA); accA = fmaf(m[4 * i + 3], a.w, accA);
      accB = fmaf(hv[4 * i + 0], b.x, accB); accB = fmaf(hv[4 * i + 1], b.y, accB);
      accB = fmaf(hv[4 * i + 2], b.z, accB); accB = fmaf(hv[4 * i + 3], b.w, accB);
    }
    rr[j] = sigmoidf_(accA + accB);
  }
#pragma unroll 4
  for (int j = 0; j < 32; ++j) {  // z gate: rows 32+j
    int row = 32 + j;
    float accA = bih_s[row], accB = bhh_s[row];
    const float4* wi = (const float4*)&wih_s[row * 32];
    const float4* wh = (const float4*)&whh_s[row * 32];
#pragma unroll
    for (int i = 0; i < 8; ++i) {
      float4 a = wi[i], b = wh[i];
      accA = fmaf(m[4 * i + 0], a.x, accA); accA = fmaf(m[4 * i + 1], a.y, accA);
      accA = fmaf(m[4 * i + 2], a.z, accA); accA = fmaf(m[4 * i + 3], a.w, accA);
      accB = fmaf(hv[4 * i + 0], b.x, accB); accB = fmaf(hv[4 * i + 1], b.y, accB);
      accB = fmaf(hv[4 * i + 2], b.z, accB); accB = fmaf(hv[4 * i + 3], b.w, accB);
    }
    zz[j] = sigmoidf_(accA + accB);
  }
#pragma unroll 4
  for (int j = 0; j < 32; ++j) {  // n gate: rows 64+j ; result -> zz[j]
    int row = 64 + j;
    float accA = bih_s[row], accB = bhh_s[row];
    const float4* wi = (const float4*)&wih_s[row * 32];
    const float4* wh = (const float4*)&whh_s[row * 32];
#pragma unroll
    for (int i = 0; i < 8; ++i) {
      float4 a = wi[i], b = wh[i];
      accA = fmaf(m[4 * i + 0], a.x, accA); accA = fmaf(m[4 * i + 1], a.y, accA);
      accA = fmaf(m[4 * i + 2], a.z, accA); accA = fmaf(m[4 * i + 3], a.w, accA);
      accB = fmaf(hv[4 * i + 0], b.x, accB); accB = fmaf(hv[4 * i + 1], b.y, accB);
      accB = fmaf(hv[4 * i + 2], b.z, accB); accB = fmaf(hv[4 * i + 3], b.w, accB);
    }
    float ng = tanhf(accA + rr[j] * accB);
    zz[j] = (1.f - zz[j]) * ng + zz[j] * hv[j];
  }
  float4* hw = (float4*)(h + (size_t)n * 32);
#pragma unroll
  for (int i = 0; i < 8; ++i)
    hw[i] = make_float4(zz[4 * i + 0], zz[4 * i + 1], zz[4 * i + 2], zz[4 * i + 3]);
}

// Set2Set LSTM cell: thread per (graph, j). q_star = [hl_in, rpool].
__global__ __launch_bounds__(256) void k_lstm(const float* __restrict__ hl_in, const float* __restrict__ cl_in,
                                              const float* __restrict__ rpool,
                                              float* __restrict__ hl_out, float* __restrict__ cl_out,
                                              const float* __restrict__ Wih, const float* __restrict__ Whh,
                                              const float* __restrict__ bih, const float* __restrict__ bhh) {
  __shared__ float wih_s[128 * 64];
  __shared__ float whh_s[128 * 32];
  __shared__ float bsum[128];
  for (int i = threadIdx.x; i < 128 * 64; i += 256) wih_s[i] = Wih[i];
  for (int i = threadIdx.x; i < 128 * 32; i += 256) whh_s[i] = Whh[i];
  for (int i = threadIdx.x; i < 128; i += 256) bsum[i] = bih[i] + bhh[i];
  __syncthreads();
  int t = blockIdx.x * 256 + threadIdx.x;
  int g = t >> 5, j = t & 31;
  if (g >= kG) return;
  float qa[32], qb[32];
  const float4* hp = (const float4*)(hl_in + (size_t)g * 32);
  const float4* rp = (const float4*)(rpool + (size_t)g * 32);
#pragma unroll
  for (int i = 0; i < 8; ++i) {
    float4 a = hp[i];
    qa[4 * i + 0] = a.x; qa[4 * i + 1] = a.y; qa[4 * i + 2] = a.z; qa[4 * i + 3] = a.w;
    float4 b = rp[i];
    qb[4 * i + 0] = b.x; qb[4 * i + 1] = b.y; qb[4 * i + 2] = b.z; qb[4 * i + 3] = b.w;
  }
  float v[4];
#pragma unroll
  for (int gate = 0; gate < 4; ++gate) {
    int row = gate * 32 + j;
    float acc = bsum[row];
    const float4* wi = (const float4*)&wih_s[row * 64];
    const float4* wh = (const float4*)&whh_s[row * 32];
#pragma unroll
    for (int i = 0; i < 8; ++i) {
      float4 a = wi[i];
      acc = fmaf(qa[4 * i + 0], a.x, acc); acc = fmaf(qa[4 * i + 1], a.y, acc);
      acc = fmaf(qa[4 * i + 2], a.z, acc); acc = fmaf(qa[4 * i + 3], a.w, acc);
    }
#pragma unroll
    for (int i = 0; i < 8; ++i) {
      float4 a = wi[8 + i];
      acc = fmaf(qb[4 * i + 0], a.x, acc); acc = fmaf(qb[4 * i + 1], a.y, acc);
      acc = fmaf(qb[4 * i + 2], a.z, acc); acc = fmaf(qb[4 * i + 3], a.w, acc);
    }
#pragma unroll
    for (int i = 0; i < 8; ++i) {
      float4 a = wh[i];
      acc = fmaf(qa[4 * i + 0], a.x, acc); acc = fmaf(qa[4 * i + 1], a.y, acc);
      acc = fmaf(qa[4 * i + 2], a.z, acc); acc = fmaf(qa[4 * i + 3], a.w, acc);
    }
    v[gate] = acc;
  }
  float ig = sigmoidf_(v[0]);
  float fg = sigmoidf_(v[1]);
  float gg = tanhf(v[2]);
  float og = sigmoidf_(v[3]);
  float c = fg * cl_in[(size_t)g * 32 + j] + ig * gg;
  cl_out[(size_t)g * 32 + j] = c;
  hl_out[(size_t)g * 32 + j] = og * tanhf(c);
}

// Per-graph softmax attention + weighted pool. One wave per graph; batch sorted.
__global__ void k_attn(const float* __restrict__ h, const float* __restrict__ hl,
                       const int* __restrict__ starts, float* __restrict__ rpool) {
  int wv = (blockIdx.x * blockDim.x + threadIdx.x) >> 6;
  if (wv >= kG) return;
  int lane = threadIdx.x & 63;
  int o = lane & 31;
  int s = starts[wv], e = starts[wv + 1];
  float q = hl[(size_t)wv * 32 + o];
  float mx = -3.0e38f;
  for (int n0 = s; n0 < e; n0 += 2) {
    int n = n0 + (lane >> 5);
    float val = (n < e) ? h[(size_t)n * 32 + o] * q : 0.f;
#pragma unroll
    for (int d = 16; d; d >>= 1) val += __shfl_xor(val, d, 32);
    if (n < e) mx = fmaxf(mx, val);
  }
  mx = fmaxf(mx, __shfl_xor(mx, 32));
  float den = 0.f, rp = 0.f;
  for (int n0 = s; n0 < e; n0 += 2) {
    int n = n0 + (lane >> 5);
    float hvo = 0.f, val = 0.f;
    if (n < e) { hvo = h[(size_t)n * 32 + o]; val = hvo * q; }
#pragma unroll
    for (int d = 16; d; d >>= 1) val += __shfl_xor(val, d, 32);
    if (n < e) {
      float p = expf(val - mx);
      den += p;
      rp = fmaf(p, hvo, rp);
    }
  }
  den += __shfl_xor(den, 32);
  rp += __shfl_xor(rp, 32);
  if (lane < 32) rpool[(size_t)wv * 32 + o] = (e > s) ? rp / den : 0.f;
}

__global__ void k_pred(const float* __restrict__ hl_f, const float* __restrict__ rpool,
                       const float* __restrict__ pw, const float* __restrict__ pb,
                       float* __restrict__ out) {
  int g = blockIdx.x * blockDim.x + threadIdx.x;
  if (g >= kG) return;
  float acc = pb[0];
#pragma unroll 4
  for (int i = 0; i < 32; ++i) acc = fmaf(hl_f[(size_t)g * 32 + i], pw[i], acc);
#pragma unroll 4
  for (int i = 0; i < 32; ++i) acc = fmaf(rpool[(size_t)g * 32 + i], pw[32 + i], acc);
  out[g] = acc;
}

}  // namespace

extern "C" void kernel_launch(void* const* d_in, const int* in_sizes, int n_in,
                              void* d_out, int out_size, void* d_ws, size_t ws_size,
                              hipStream_t stream) {
  const float* x     = (const float*)d_in[0];
  const int*   eidx  = (const int*)d_in[1];
  const float* eattr = (const float*)d_in[2];
  const int*   batch = (const int*)d_in[3];
  const float* lin_w = (const float*)d_in[4];
  const float* lin_b = (const float*)d_in[5];
  const float* e_w1  = (const float*)d_in[6];
  const float* e_b1  = (const float*)d_in[7];
  const float* e_w2  = (const float*)d_in[8];
  const float* e_b2  = (const float*)d_in[9];
  const float* gwih  = (const float*)d_in[10];
  const float* gwhh  = (const float*)d_in[11];
  const float* gbih  = (const float*)d_in[12];
  const float* gbhh  = (const float*)d_in[13];
  const float* lwih  = (const float*)d_in[14];
  const float* lwhh  = (const float*)d_in[15];
  const float* lbih  = (const float*)d_in[16];
  const float* lbhh  = (const float*)d_in[17];
  const float* pw    = (const float*)d_in[18];
  const float* pb    = (const float*)d_in[19];
  const int* srcp = eidx;
  const int* dstp = eidx + kE;

  float* ws = (float*)d_ws;
  size_t off = 0;
  auto alloc = [&](size_t nel) {
    float* p = ws + off;
    off += (nel + 255) & ~(size_t)255;
    return p;
  };
  float* hbuf  = alloc((size_t)kN * 32);
  float* agg   = alloc((size_t)kN * 32);
  float* denom = alloc(kN);
  float* ehb   = alloc((size_t)kE * 64);
  float* hl0   = alloc((size_t)kG * 32);
  float* hl1   = alloc((size_t)kG * 32);
  float* cl0   = alloc((size_t)kG * 32);
  float* cl1   = alloc((size_t)kG * 32);
  float* rpool = alloc((size_t)kG * 32);
  int* starts  = (int*)alloc(kG + 1);
  if (ws_size / 4 < off) return;  // workspace too small for even the base layout

  size_t avail = ws_size / 4 - off;
  long long chunk = (long long)(avail / 1024) & ~63LL;  // edges whose W rows fit
  if (chunk > kE) chunk = kE;
  float* Wbuf = ws + off;
  bool full = (chunk >= kE);

  hipMemsetAsync(denom, 0, (size_t)kN * 4, stream);
  hipMemsetAsync(hl0, 0, (size_t)kG * 32 * 4, stream);
  hipMemsetAsync(cl0, 0, (size_t)kG * 32 * 4, stream);
  hipMemsetAsync(rpool, 0, (size_t)kG * 32 * 4, stream);

  k_starts<<<(kG + 1 + 255) / 256, 256, 0, stream>>>(batch, starts);
  k_node_init<<<(kN + 255) / 256, 256, 0, stream>>>(x, lin_w, lin_b, hbuf);
  k_edge_h<<<(kE + 255) / 256, 256, 0, stream>>>(eattr, e_w1, e_b1, ehb);
  k_deg<<<(kE + 255) / 256, 256, 0, stream>>>(dstp, denom);

  if (full) {
    dim3 g((kE + 63) / 64, 8);
    k_we_gemm<<<g, 256, 0, stream>>>(ehb, e_w2, e_b2, Wbuf, 0, kE);
  }

  for (int step = 0; step < 3; ++step) {
    hipMemsetAsync(agg, 0, (size_t)kN * 32 * 4, stream);
    if (full) {
      k_msg<<<((size_t)kE * 32 + 255) / 256, 256, 0, stream>>>(Wbuf, hbuf, srcp, dstp, agg, 0, kE);
    } else if (chunk >= 64) {
      for (long long e0 = 0; e0 < kE; e0 += chunk) {
        int ne = (int)((kE - e0 < chunk) ? (kE - e0) : chunk);
        dim3 g((ne + 63) / 64, 8);
        k_we_gemm<<<g, 256, 0, stream>>>(ehb, e_w2, e_b2, Wbuf, (int)e0, ne);
        k_msg<<<((size_t)ne * 32 + 255) / 256, 256, 0, stream>>>(Wbuf, hbuf, srcp, dstp, agg, (int)e0, ne);
      }
    } else {
      k_msg_direct<<<((size_t)kE * 32 + 255) / 256, 256, 0, stream>>>(ehb, e_w2, e_b2, hbuf, srcp, dstp, agg);
    }
    k_gru<<<(kN + 255) / 256, 256, 0, stream>>>(hbuf, agg, denom, gwih, gwhh, gbih, gbhh);
  }

  float* hls[2] = {hl0, hl1};
  float* cls[2] = {cl0, cl1};
  int a = 0;
  for (int t = 0; t < 3; ++t) {
    int b = a ^ 1;
    k_lstm<<<(kG * 32 + 255) / 256, 256, 0, stream>>>(hls[a], cls[a], rpool, hls[b], cls[b],
                                                      lwih, lwhh, lbih, lbhh);
    k_attn<<<(kG * 64 + 255) / 256, 256, 0, stream>>>(hbuf, hls[b], starts, rpool);
    a = b;
  }
  k_pred<<<(kG + 255) / 256, 256, 0, stream>>>(hls[a], rpool, pw, pb, (float*)d_out);
}

// Round 2
// 1049.121 us; speedup vs baseline: 1.9861x; 1.9861x over previous
//
#include <hip/hip_runtime.h>
#include <hip/hip_bf16.h>

namespace {
constexpr int kN = 50000;   // nodes
constexpr int kE = 250000;  // edges
constexpr int kG = 2500;    // graphs

__device__ __forceinline__ float sigmoidf_(float x) { return 1.0f / (1.0f + expf(-x)); }

// starts[g] = first node index with batch[n] >= g (batch is sorted). g in [0, kG].
__global__ void k_starts(const int* __restrict__ batch, int* __restrict__ starts) {
  int g = blockIdx.x * blockDim.x + threadIdx.x;
  if (g > kG) return;
  int lo = 0, hi = kN;
  while (lo < hi) {
    int mid = (lo + hi) >> 1;
    if (batch[mid] < g) lo = mid + 1; else hi = mid;
  }
  starts[g] = lo;
}

// h[n,:] = relu(x[n,:] @ lin_w + lin_b)   [N,32] = [N,32]@[32,32]
__global__ __launch_bounds__(256) void k_node_init(const float* __restrict__ x,
                                                   const float* __restrict__ lin_w,
                                                   const float* __restrict__ lin_b,
                                                   float* __restrict__ h) {
  __shared__ float ws[32 * 32];
  __shared__ float bs[32];
  for (int i = threadIdx.x; i < 1024; i += 256) ws[i] = lin_w[i];
  if (threadIdx.x < 32) bs[threadIdx.x] = lin_b[threadIdx.x];
  __syncthreads();
  int n = blockIdx.x * 256 + threadIdx.x;
  if (n >= kN) return;
  float xv[32];
  const float4* xp = (const float4*)(x + (size_t)n * 32);
#pragma unroll
  for (int i = 0; i < 8; ++i) {
    float4 v = xp[i];
    xv[4 * i + 0] = v.x; xv[4 * i + 1] = v.y; xv[4 * i + 2] = v.z; xv[4 * i + 3] = v.w;
  }
  float acc[32];
#pragma unroll
  for (int o = 0; o < 32; ++o) acc[o] = bs[o];
  for (int i = 0; i < 32; ++i) {
    float a = xv[i];
    const float4* wr = (const float4*)&ws[i * 32];
#pragma unroll
    for (int o4 = 0; o4 < 8; ++o4) {
      float4 w = wr[o4];
      acc[4 * o4 + 0] = fmaf(a, w.x, acc[4 * o4 + 0]);
      acc[4 * o4 + 1] = fmaf(a, w.y, acc[4 * o4 + 1]);
      acc[4 * o4 + 2] = fmaf(a, w.z, acc[4 * o4 + 2]);
      acc[4 * o4 + 3] = fmaf(a, w.w, acc[4 * o4 + 3]);
    }
  }
  float4* hp = (float4*)(h + (size_t)n * 32);
#pragma unroll
  for (int i = 0; i < 8; ++i) {
    float4 v;
    v.x = fmaxf(acc[4 * i + 0], 0.f);
    v.y = fmaxf(acc[4 * i + 1], 0.f);
    v.z = fmaxf(acc[4 * i + 2], 0.f);
    v.w = fmaxf(acc[4 * i + 3], 0.f);
    hp[i] = v;
  }
}

// eh[e,:] = relu(edge_attr[e,:] @ e_w1 + e_b1)   [E,64] = [E,16]@[16,64]
__global__ __launch_bounds__(256) void k_edge_h(const float* __restrict__ ea,
                                                const float* __restrict__ w1,
                                                const float* __restrict__ b1,
                                                float* __restrict__ eh) {
  __shared__ float ws[16 * 64];
  __shared__ float bs[64];
  for (int i = threadIdx.x; i < 1024; i += 256) ws[i] = w1[i];
  if (threadIdx.x < 64) bs[threadIdx.x] = b1[threadIdx.x];
  __syncthreads();
  int e = blockIdx.x * 256 + threadIdx.x;
  if (e >= kE) return;
  float av[16];
  const float4* ap = (const float4*)(ea + (size_t)e * 16);
#pragma unroll
  for (int i = 0; i < 4; ++i) {
    float4 v = ap[i];
    av[4 * i + 0] = v.x; av[4 * i + 1] = v.y; av[4 * i + 2] = v.z; av[4 * i + 3] = v.w;
  }
  float acc[64];
#pragma unroll
  for (int o = 0; o < 64; ++o) acc[o] = bs[o];
  for (int i = 0; i < 16; ++i) {
    float a = av[i];
    const float4* wr = (const float4*)&ws[i * 64];
#pragma unroll
    for (int o4 = 0; o4 < 16; ++o4) {
      float4 w = wr[o4];
      acc[4 * o4 + 0] = fmaf(a, w.x, acc[4 * o4 + 0]);
      acc[4 * o4 + 1] = fmaf(a, w.y, acc[4 * o4 + 1]);
      acc[4 * o4 + 2] = fmaf(a, w.z, acc[4 * o4 + 2]);
      acc[4 * o4 + 3] = fmaf(a, w.w, acc[4 * o4 + 3]);
    }
  }
  float4* op = (float4*)(eh + (size_t)e * 64);
#pragma unroll
  for (int i = 0; i < 16; ++i) {
    float4 v;
    v.x = fmaxf(acc[4 * i + 0], 0.f);
    v.y = fmaxf(acc[4 * i + 1], 0.f);
    v.z = fmaxf(acc[4 * i + 2], 0.f);
    v.w = fmaxf(acc[4 * i + 3], 0.f);
    op[i] = v;
  }
}

__global__ void k_deg(const int* __restrict__ dst, float* __restrict__ denom) {
  int e = blockIdx.x * blockDim.x + threadIdx.x;
  if (e < kE) atomicAdd(&denom[dst[e]], 1.0f);
}

// ---- counting sort of edges by src ----
__global__ void k_hist(const int* __restrict__ src, int* __restrict__ cnt) {
  int e = blockIdx.x * blockDim.x + threadIdx.x;
  if (e < kE) atomicAdd(&cnt[src[e]], 1);
}

// exclusive scan of cnt[0..kN) -> offs[0..kN], single block of 1024 threads
__global__ __launch_bounds__(1024) void k_scan(const int* __restrict__ cnt, int* __restrict__ offs) {
  __shared__ int wsum[16];
  __shared__ int wpre[16];
  __shared__ int carry_s;
  const int tid = threadIdx.x;
  const int lane = tid & 63, wv = tid >> 6;
  if (tid == 0) carry_s = 0;
  __syncthreads();
  for (int base = 0; base < kN; base += 1024) {
    int i = base + tid;
    int v = (i < kN) ? cnt[i] : 0;
    int x = v;
#pragma unroll
    for (int d = 1; d < 64; d <<= 1) {
      int t = __shfl_up(x, d, 64);
      if (lane >= d) x += t;
    }
    if (lane == 63) wsum[wv] = x;
    __syncthreads();
    if (wv == 0) {
      int y = (lane < 16) ? wsum[lane] : 0;
#pragma unroll
      for (int d = 1; d < 16; d <<= 1) {
        int t = __shfl_up(y, d, 64);
        if (lane >= d && lane < 16) y += t;
      }
      if (lane < 16) wpre[lane] = y - wsum[lane];  // exclusive wave prefix
    }
    __syncthreads();
    int carry = carry_s;
    if (i < kN) offs[i] = carry + wpre[wv] + (x - v);
    __syncthreads();
    if (tid == 0) carry_s = carry + wpre[15] + wsum[15];
    __syncthreads();
  }
  if (tid == 0) offs[kN] = carry_s;
}

__global__ void k_scatter(const int* __restrict__ src, const int* __restrict__ dst,
                          const int* __restrict__ offs, int* __restrict__ cur,
                          int* __restrict__ es_e, int* __restrict__ es_src,
                          int* __restrict__ es_dst) {
  int e = blockIdx.x * blockDim.x + threadIdx.x;
  if (e >= kE) return;
  int s = src[e];
  int pos = offs[s] + atomicAdd(&cur[s], 1);
  es_e[pos] = e;
  es_src[pos] = s;
  es_dst[pos] = dst[e];
}

// ---- fused conv: per block of 8 nodes, compute T[n,k,o]=sum_a h[n,a]*w2[k,a*32+o]
// in LDS, then contract the nodes' out-edges: msg = hb2 + sum_k eh[e,k]*T, atomic to agg.
__global__ __launch_bounds__(256, 2) void k_conv(const float* __restrict__ h,
                                                 const float* __restrict__ eh,
                                                 const float* __restrict__ w2,
                                                 const float* __restrict__ b2,
                                                 const int* __restrict__ es_e,
                                                 const int* __restrict__ es_src,
                                                 const int* __restrict__ es_dst,
                                                 const int* __restrict__ offs,
                                                 float* __restrict__ agg) {
  __shared__ float Ts[8][64][32];
  __shared__ float hs[8][32];
  __shared__ float hb2[8][32];
  const int n0 = blockIdx.x * 8;
  const int t = threadIdx.x;
  const int kg = t >> 5;  // 0..7
  const int o = t & 31;
  hs[kg][o] = h[(size_t)(n0 + kg) * 32 + o];
  __syncthreads();
  // hb2[n][o] = sum_a h[n,a]*b2[a*32+o]  (thread (kg=n, o))
  {
    float acc = 0.f;
#pragma unroll
    for (int a = 0; a < 32; ++a) acc = fmaf(hs[kg][a], b2[a * 32 + o], acc);
    hb2[kg][o] = acc;
  }
  // T: thread (kg,o) computes T[n][kg*8+kk][o] for n 0..7, kk 0..7
  float acc[8][8];
#pragma unroll
  for (int n = 0; n < 8; ++n)
#pragma unroll
    for (int kk = 0; kk < 8; ++kk) acc[n][kk] = 0.f;
  const float* w2p = w2 + (size_t)kg * 8 * 1024 + o;
#pragma unroll 2
  for (int a4 = 0; a4 < 8; ++a4) {
    float4 hv[8];
#pragma unroll
    for (int n = 0; n < 8; ++n) hv[n] = *(const float4*)&hs[n][a4 * 4];
#pragma unroll
    for (int j = 0; j < 4; ++j) {
      const int a = a4 * 4 + j;
      float w[8];
#pragma unroll
      for (int kk = 0; kk < 8; ++kk) w[kk] = w2p[(size_t)kk * 1024 + a * 32];
#pragma unroll
      for (int n = 0; n < 8; ++n) {
        float hval = (j == 0) ? hv[n].x : (j == 1) ? hv[n].y : (j == 2) ? hv[n].z : hv[n].w;
#pragma unroll
        for (int kk = 0; kk < 8; ++kk) acc[n][kk] = fmaf(hval, w[kk], acc[n][kk]);
      }
    }
  }
#pragma unroll
  for (int n = 0; n < 8; ++n)
#pragma unroll
    for (int kk = 0; kk < 8; ++kk) Ts[n][kg * 8 + kk][o] = acc[n][kk];
  __syncthreads();
  // edge contraction: one 32-lane group per edge
  const int es = offs[n0], ee = offs[n0 + 8];
  for (int ei = es + kg; ei < ee; ei += 8) {
    const int e = es_e[ei];
    const int nl = es_src[ei] - n0;
    const int d = es_dst[ei];
    const float ehA = eh[(size_t)e * 64 + o];
    const float ehB = eh[(size_t)e * 64 + 32 + o];
    float m = hb2[nl][o];
#pragma unroll
    for (int k = 0; k < 32; ++k) m = fmaf(__shfl(ehA, k, 32), Ts[nl][k][o], m);
#pragma unroll
    for (int k = 0; k < 32; ++k) m = fmaf(__shfl(ehB, k, 32), Ts[nl][32 + k][o], m);
    atomicAdd(&agg[(size_t)d * 32 + o], m);
  }
}

// GRU cell, in-place h update. m = relu(agg/denom)
__global__ __launch_bounds__(256) void k_gru(float* __restrict__ h, const float* __restrict__ agg,
                                             const float* __restrict__ denom,
                                             const float* __restrict__ Wih, const float* __restrict__ Whh,
                                             const float* __restrict__ bih, const float* __restrict__ bhh) {
  __shared__ float wih_s[96 * 32];
  __shared__ float whh_s[96 * 32];
  __shared__ float bih_s[96], bhh_s[96];
  for (int i = threadIdx.x; i < 96 * 32; i += 256) { wih_s[i] = Wih[i]; whh_s[i] = Whh[i]; }
  for (int i = threadIdx.x; i < 96; i += 256) { bih_s[i] = bih[i]; bhh_s[i] = bhh[i]; }
  __syncthreads();
  int n = blockIdx.x * 256 + threadIdx.x;
  if (n >= kN) return;
  float dn = fmaxf(denom[n], 1.0f);
  float m[32], hv[32];
  const float4* ap = (const float4*)(agg + (size_t)n * 32);
  const float4* hp = (const float4*)(h + (size_t)n * 32);
#pragma unroll
  for (int i = 0; i < 8; ++i) {
    float4 a = ap[i];
    m[4 * i + 0] = fmaxf(a.x / dn, 0.f);
    m[4 * i + 1] = fmaxf(a.y / dn, 0.f);
    m[4 * i + 2] = fmaxf(a.z / dn, 0.f);
    m[4 * i + 3] = fmaxf(a.w / dn, 0.f);
    float4 b = hp[i];
    hv[4 * i + 0] = b.x; hv[4 * i + 1] = b.y; hv[4 * i + 2] = b.z; hv[4 * i + 3] = b.w;
  }
  float rr[32], zz[32];
#pragma unroll 4
  for (int j = 0; j < 32; ++j) {
    float accA = bih_s[j], accB = bhh_s[j];
    const float4* wi = (const float4*)&wih_s[j * 32];
    const float4* wh = (const float4*)&whh_s[j * 32];
#pragma unroll
    for (int i = 0; i < 8; ++i) {
      float4 a = wi[i], b = wh[i];
      accA = fmaf(m[4 * i + 0], a.x, accA); accA = fmaf(m[4 * i + 1], a.y, accA);
      accA = fmaf(m[4 * i + 2], a.z, accA); accA = fmaf(m[4 * i + 3], a.w, accA);
      accB = fmaf(hv[4 * i + 0], b.x, accB); accB = fmaf(hv[4 * i + 1], b.y, accB);
      accB = fmaf(hv[4 * i + 2], b.z, accB); accB = fmaf(hv[4 * i + 3], b.w, accB);
    }
    rr[j] = sigmoidf_(accA + accB);
  }
#pragma unroll 4
  for (int j = 0; j < 32; ++j) {
    int row = 32 + j;
    float accA = bih_s[row], accB = bhh_s[row];
    const float4* wi = (const float4*)&wih_s[row * 32];
    const float4* wh = (const float4*)&whh_s[row * 32];
#pragma unroll
    for (int i = 0; i < 8; ++i) {
      float4 a = wi[i], b = wh[i];
      accA = fmaf(m[4 * i + 0], a.x, accA); accA = fmaf(m[4 * i + 1], a.y, accA);
      accA = fmaf(m[4 * i + 2], a.z, accA); accA = fmaf(m[4 * i + 3], a.w, accA);
      accB = fmaf(hv[4 * i + 0], b.x, accB); accB = fmaf(hv[4 * i + 1], b.y, accB);
      accB = fmaf(hv[4 * i + 2], b.z, accB); accB = fmaf(hv[4 * i + 3], b.w, accB);
    }
    zz[j] = sigmoidf_(accA + accB);
  }
#pragma unroll 4
  for (int j = 0; j < 32; ++j) {
    int row = 64 + j;
    float accA = bih_s[row], accB = bhh_s[row];
    const float4* wi = (const float4*)&wih_s[row * 32];
    const float4* wh = (const float4*)&whh_s[row * 32];
#pragma unroll
    for (int i = 0; i < 8; ++i) {
      float4 a = wi[i], b = wh[i];
      accA = fmaf(m[4 * i + 0], a.x, accA); accA = fmaf(m[4 * i + 1], a.y, accA);
      accA = fmaf(m[4 * i + 2], a.z, accA); accA = fmaf(m[4 * i + 3], a.w, accA);
      accB = fmaf(hv[4 * i + 0], b.x, accB); accB = fmaf(hv[4 * i + 1], b.y, accB);
      accB = fmaf(hv[4 * i + 2], b.z, accB); accB = fmaf(hv[4 * i + 3], b.w, accB);
    }
    float ng = tanhf(accA + rr[j] * accB);
    zz[j] = (1.f - zz[j]) * ng + zz[j] * hv[j];
  }
  float4* hw = (float4*)(h + (size_t)n * 32);
#pragma unroll
  for (int i = 0; i < 8; ++i)
    hw[i] = make_float4(zz[4 * i + 0], zz[4 * i + 1], zz[4 * i + 2], zz[4 * i + 3]);
}

// Set2Set LSTM cell: thread per (graph, j). q_star = [hl_in, rpool].
__global__ __launch_bounds__(256) void k_lstm(const float* __restrict__ hl_in, const float* __restrict__ cl_in,
                                              const float* __restrict__ rpool,
                                              float* __restrict__ hl_out, float* __restrict__ cl_out,
                                              const float* __restrict__ Wih, const float* __restrict__ Whh,
                                              const float* __restrict__ bih, const float* __restrict__ bhh) {
  __shared__ float wih_s[128 * 64];
  __shared__ float whh_s[128 * 32];
  __shared__ float bsum[128];
  for (int i = threadIdx.x; i < 128 * 64; i += 256) wih_s[i] = Wih[i];
  for (int i = threadIdx.x; i < 128 * 32; i += 256) whh_s[i] = Whh[i];
  for (int i = threadIdx.x; i < 128; i += 256) bsum[i] = bih[i] + bhh[i];
  __syncthreads();
  int t = blockIdx.x * 256 + threadIdx.x;
  int g = t >> 5, j = t & 31;
  if (g >= kG) return;
  float qa[32], qb[32];
  const float4* hp = (const float4*)(hl_in + (size_t)g * 32);
  const float4* rp = (const float4*)(rpool + (size_t)g * 32);
#pragma unroll
  for (int i = 0; i < 8; ++i) {
    float4 a = hp[i];
    qa[4 * i + 0] = a.x; qa[4 * i + 1] = a.y; qa[4 * i + 2] = a.z; qa[4 * i + 3] = a.w;
    float4 b = rp[i];
    qb[4 * i + 0] = b.x; qb[4 * i + 1] = b.y; qb[4 * i + 2] = b.z; qb[4 * i + 3] = b.w;
  }
  float v[4];
#pragma unroll
  for (int gate = 0; gate < 4; ++gate) {
    int row = gate * 32 + j;
    float acc = bsum[row];
    const float4* wi = (const float4*)&wih_s[row * 64];
    const float4* wh = (const float4*)&whh_s[row * 32];
#pragma unroll
    for (int i = 0; i < 8; ++i) {
      float4 a = wi[i];
      acc = fmaf(qa[4 * i + 0], a.x, acc); acc = fmaf(qa[4 * i + 1], a.y, acc);
      acc = fmaf(qa[4 * i + 2], a.z, acc); acc = fmaf(qa[4 * i + 3], a.w, acc);
    }
#pragma unroll
    for (int i = 0; i < 8; ++i) {
      float4 a = wi[8 + i];
      acc = fmaf(qb[4 * i + 0], a.x, acc); acc = fmaf(qb[4 * i + 1], a.y, acc);
      acc = fmaf(qb[4 * i + 2], a.z, acc); acc = fmaf(qb[4 * i + 3], a.w, acc);
    }
#pragma unroll
    for (int i = 0; i < 8; ++i) {
      float4 a = wh[i];
      acc = fmaf(qa[4 * i + 0], a.x, acc); acc = fmaf(qa[4 * i + 1], a.y, acc);
      acc = fmaf(qa[4 * i + 2], a.z, acc); acc = fmaf(qa[4 * i + 3], a.w, acc);
    }
    v[gate] = acc;
  }
  float ig = sigmoidf_(v[0]);
  float fg = sigmoidf_(v[1]);
  float gg = tanhf(v[2]);
  float og = sigmoidf_(v[3]);
  float c = fg * cl_in[(size_t)g * 32 + j] + ig * gg;
  cl_out[(size_t)g * 32 + j] = c;
  hl_out[(size_t)g * 32 + j] = og * tanhf(c);
}

// Per-graph softmax attention + weighted pool. One wave per graph; batch sorted.
__global__ void k_attn(const float* __restrict__ h, const float* __restrict__ hl,
                       const int* __restrict__ starts, float* __restrict__ rpool) {
  int wv = (blockIdx.x * blockDim.x + threadIdx.x) >> 6;
  if (wv >= kG) return;
  int lane = threadIdx.x & 63;
  int o = lane & 31;
  int s = starts[wv], e = starts[wv + 1];
  float q = hl[(size_t)wv * 32 + o];
  float mx = -3.0e38f;
  for (int n0 = s; n0 < e; n0 += 2) {
    int n = n0 + (lane >> 5);
    float val = (n < e) ? h[(size_t)n * 32 + o] * q : 0.f;
#pragma unroll
    for (int d = 16; d; d >>= 1) val += __shfl_xor(val, d, 32);
    if (n < e) mx = fmaxf(mx, val);
  }
  mx = fmaxf(mx, __shfl_xor(mx, 32));
  float den = 0.f, rp = 0.f;
  for (int n0 = s; n0 < e; n0 += 2) {
    int n = n0 + (lane >> 5);
    float hvo = 0.f, val = 0.f;
    if (n < e) { hvo = h[(size_t)n * 32 + o]; val = hvo * q; }
#pragma unroll
    for (int d = 16; d; d >>= 1) val += __shfl_xor(val, d, 32);
    if (n < e) {
      float p = expf(val - mx);
      den += p;
      rp = fmaf(p, hvo, rp);
    }
  }
  den += __shfl_xor(den, 32);
  rp += __shfl_xor(rp, 32);
  if (lane < 32) rpool[(size_t)wv * 32 + o] = (e > s) ? rp / den : 0.f;
}

__global__ void k_pred(const float* __restrict__ hl_f, const float* __restrict__ rpool,
                       const float* __restrict__ pw, const float* __restrict__ pb,
                       float* __restrict__ out) {
  int g = blockIdx.x * blockDim.x + threadIdx.x;
  if (g >= kG) return;
  float acc = pb[0];
#pragma unroll 4
  for (int i = 0; i < 32; ++i) acc = fmaf(hl_f[(size_t)g * 32 + i], pw[i], acc);
#pragma unroll 4
  for (int i = 0; i < 32; ++i) acc = fmaf(rpool[(size_t)g * 32 + i], pw[32 + i], acc);
  out[g] = acc;
}

}  // namespace

extern "C" void kernel_launch(void* const* d_in, const int* in_sizes, int n_in,
                              void* d_out, int out_size, void* d_ws, size_t ws_size,
                              hipStream_t stream) {
  const float* x     = (const float*)d_in[0];
  const int*   eidx  = (const int*)d_in[1];
  const float* eattr = (const float*)d_in[2];
  const int*   batch = (const int*)d_in[3];
  const float* lin_w = (const float*)d_in[4];
  const float* lin_b = (const float*)d_in[5];
  const float* e_w1  = (const float*)d_in[6];
  const float* e_b1  = (const float*)d_in[7];
  const float* e_w2  = (const float*)d_in[8];
  const float* e_b2  = (const float*)d_in[9];
  const float* gwih  = (const float*)d_in[10];
  const float* gwhh  = (const float*)d_in[11];
  const float* gbih  = (const float*)d_in[12];
  const float* gbhh  = (const float*)d_in[13];
  const float* lwih  = (const float*)d_in[14];
  const float* lwhh  = (const float*)d_in[15];
  const float* lbih  = (const float*)d_in[16];
  const float* lbhh  = (const float*)d_in[17];
  const float* pw    = (const float*)d_in[18];
  const float* pb    = (const float*)d_in[19];
  const int* srcp = eidx;
  const int* dstp = eidx + kE;

  float* ws = (float*)d_ws;
  size_t off = 0;
  auto alloc = [&](size_t nel) {
    float* p = ws + off;
    off += (nel + 255) & ~(size_t)255;
    return p;
  };
  float* hbuf  = alloc((size_t)kN * 32);
  float* agg   = alloc((size_t)kN * 32);
  float* denom = alloc(kN);
  float* ehb   = alloc((size_t)kE * 64);
  float* hl0   = alloc((size_t)kG * 32);
  float* hl1   = alloc((size_t)kG * 32);
  float* cl0   = alloc((size_t)kG * 32);
  float* cl1   = alloc((size_t)kG * 32);
  float* rpool = alloc((size_t)kG * 32);
  int* starts  = (int*)alloc(kG + 1);
  int* cnt     = (int*)alloc(kN);
  int* cur     = (int*)alloc(kN);
  int* offs    = (int*)alloc(kN + 1);
  int* es_e    = (int*)alloc(kE);
  int* es_src  = (int*)alloc(kE);
  int* es_dst  = (int*)alloc(kE);
  if (ws_size / 4 < off) return;

  hipMemsetAsync(denom, 0, (size_t)kN * 4, stream);
  hipMemsetAsync(hl0, 0, (size_t)kG * 32 * 4, stream);
  hipMemsetAsync(cl0, 0, (size_t)kG * 32 * 4, stream);
  hipMemsetAsync(rpool, 0, (size_t)kG * 32 * 4, stream);
  hipMemsetAsync(cnt, 0, (size_t)kN * 4, stream);
  hipMemsetAsync(cur, 0, (size_t)kN * 4, stream);

  k_starts<<<(kG + 1 + 255) / 256, 256, 0, stream>>>(batch, starts);
  k_node_init<<<(kN + 255) / 256, 256, 0, stream>>>(x, lin_w, lin_b, hbuf);
  k_edge_h<<<(kE + 255) / 256, 256, 0, stream>>>(eattr, e_w1, e_b1, ehb);
  k_deg<<<(kE + 255) / 256, 256, 0, stream>>>(dstp, denom);

  // one-time counting sort of edges by src
  k_hist<<<(kE + 255) / 256, 256, 0, stream>>>(srcp, cnt);
  k_scan<<<1, 1024, 0, stream>>>(cnt, offs);
  k_scatter<<<(kE + 255) / 256, 256, 0, stream>>>(srcp, dstp, offs, cur, es_e, es_src, es_dst);

  for (int step = 0; step < 3; ++step) {
    hipMemsetAsync(agg, 0, (size_t)kN * 32 * 4, stream);
    k_conv<<<kN / 8, 256, 0, stream>>>(hbuf, ehb, e_w2, e_b2, es_e, es_src, es_dst, offs, agg);
    k_gru<<<(kN + 255) / 256, 256, 0, stream>>>(hbuf, agg, denom, gwih, gwhh, gbih, gbhh);
  }

  float* hls[2] = {hl0, hl1};
  float* cls[2] = {cl0, cl1};
  int a = 0;
  for (int t = 0; t < 3; ++t) {
    int b = a ^ 1;
    k_lstm<<<(kG * 32 + 255) / 256, 256, 0, stream>>>(hls[a], cls[a], rpool, hls[b], cls[b],
                                                      lwih, lwhh, lbih, lbhh);
    k_attn<<<(kG * 64 + 255) / 256, 256, 0, stream>>>(hbuf, hls[b], starts, rpool);
    a = b;
  }
  k_pred<<<(kG + 255) / 256, 256, 0, stream>>>(hls[a], rpool, pw, pb, (float*)d_out);
}